// Round 4
// baseline (61.700 us; speedup 1.0000x reference)
//
#include <hip/hip_runtime.h>

#define N_NODES 100000
#define D 64
#define ALPHA 0.2f

// ---------------------------------------------------------------------------
// Kernel 1: build row_ptr[N+1] from sorted edge_row.
// ---------------------------------------------------------------------------
__global__ void __launch_bounds__(256) build_row_ptr(
    const int* __restrict__ erow, int* __restrict__ row_ptr, int n_edges) {
    const int e = blockIdx.x * blockDim.x + threadIdx.x;
    if (e >= n_edges) return;
    const int r = erow[e];
    const int rprev = (e == 0) ? -1 : erow[e - 1];
    for (int rr = rprev + 1; rr <= r; ++rr) row_ptr[rr] = e;
    if (e == n_edges - 1) {
        for (int rr = r + 1; rr <= N_NODES; ++rr) row_ptr[rr] = n_edges;
    }
}

// ---------------------------------------------------------------------------
// Kernel 2: convert h (fp32, N*64) -> bf16 (RNE), packed 2 per uint.
// ---------------------------------------------------------------------------
__global__ void __launch_bounds__(256) convert_h_bf16(
    const float* __restrict__ h, unsigned int* __restrict__ hb_packed, int n4) {
    for (int i = blockIdx.x * blockDim.x + threadIdx.x; i < n4;
         i += gridDim.x * blockDim.x) {
        const float4 f = reinterpret_cast<const float4*>(h)[i];
        union { float f; unsigned int u; } c0, c1, c2, c3;
        c0.f = f.x; c1.f = f.y; c2.f = f.z; c3.f = f.w;
        unsigned int b0 = (c0.u + 0x7FFFu + ((c0.u >> 16) & 1u)) >> 16;
        unsigned int b1 = (c1.u + 0x7FFFu + ((c1.u >> 16) & 1u)) >> 16;
        unsigned int b2 = (c2.u + 0x7FFFu + ((c2.u >> 16) & 1u)) >> 16;
        unsigned int b3 = (c3.u + 0x7FFFu + ((c3.u >> 16) & 1u)) >> 16;
        uint2 o;
        o.x = b0 | (b1 << 16);
        o.y = b2 | (b3 << 16);
        reinterpret_cast<uint2*>(hb_packed)[i] = o;
    }
}

__device__ __forceinline__ float bf_lo(unsigned int u) {
    union { unsigned int u; float f; } c; c.u = u << 16; return c.f;
}
__device__ __forceinline__ float bf_hi(unsigned int u) {
    union { unsigned int u; float f; } c; c.u = u & 0xFFFF0000u; return c.f;
}

// ---------------------------------------------------------------------------
// Kernel 3: 8 groups x 8 lanes per wave; one ROW per group. Lane keeps 8 dims
// of its group's row in registers -> no cross-lane reduction at all. Inner
// loop: 4 edges/group/iter with independent addresses -> ~12 VMEM in flight
// per wave. Groups that finish early are exec-masked (no traffic).
// Grid: N_NODES*8 threads total = 3125 blocks of 256 (exact, no tail).
// ---------------------------------------------------------------------------
__global__ void __launch_bounds__(256) appnp_group_bf16(
    const int* __restrict__ row_ptr,
    const int* __restrict__ ecol,
    const float* __restrict__ evals,
    const unsigned short* __restrict__ hb,   // bf16 h, row stride 64 elems
    const float* __restrict__ h0,
    float* __restrict__ out) {
    const int tid = blockIdx.x * blockDim.x + threadIdx.x;
    const int row = tid >> 3;          // one row per 8-lane group
    const int l = threadIdx.x & 7;     // dim octet: dims 8l..8l+7
    if (row >= N_NODES) return;

    const int s   = row_ptr[row];
    const int len = row_ptr[row + 1] - s;

    float a0 = 0.f, a1 = 0.f, a2 = 0.f, a3 = 0.f,
          a4 = 0.f, a5 = 0.f, a6 = 0.f, a7 = 0.f;

    const unsigned short* hl = hb + (l << 3);  // lane's 16-B column slice

    for (int i = 0; i < len; i += 4) {
        // 4 independent edges for this group; per-edge exec-masked.
        #define EDGE(K)                                                        \
        if (i + K < len) {                                                     \
            const int e = s + i + K;                                           \
            const int c = ecol[e];                                             \
            const float v = evals[e];                                          \
            const uint4 p = *reinterpret_cast<const uint4*>(                   \
                hl + ((size_t)c << 6));                                        \
            a0 = fmaf(v, bf_lo(p.x), a0); a1 = fmaf(v, bf_hi(p.x), a1);        \
            a2 = fmaf(v, bf_lo(p.y), a2); a3 = fmaf(v, bf_hi(p.y), a3);        \
            a4 = fmaf(v, bf_lo(p.z), a4); a5 = fmaf(v, bf_hi(p.z), a5);        \
            a6 = fmaf(v, bf_lo(p.w), a6); a7 = fmaf(v, bf_hi(p.w), a7);        \
        }
        EDGE(0) EDGE(1) EDGE(2) EDGE(3)
        #undef EDGE
    }

    // Epilogue: lane owns out[row][8l..8l+7]. Wave-wide this is one
    // contiguous 2-KB span (tid*32 B) -> perfectly coalesced.
    const size_t o = ((size_t)row << 6) + (l << 3);
    const float4 h0a = *reinterpret_cast<const float4*>(&h0[o]);
    const float4 h0b = *reinterpret_cast<const float4*>(&h0[o + 4]);
    const float w = 1.0f - ALPHA;
    float4 oA, oB;
    oA.x = fmaf(w, a0, ALPHA * h0a.x);
    oA.y = fmaf(w, a1, ALPHA * h0a.y);
    oA.z = fmaf(w, a2, ALPHA * h0a.z);
    oA.w = fmaf(w, a3, ALPHA * h0a.w);
    oB.x = fmaf(w, a4, ALPHA * h0b.x);
    oB.y = fmaf(w, a5, ALPHA * h0b.y);
    oB.z = fmaf(w, a6, ALPHA * h0b.z);
    oB.w = fmaf(w, a7, ALPHA * h0b.w);
    *reinterpret_cast<float4*>(&out[o])     = oA;
    *reinterpret_cast<float4*>(&out[o + 4]) = oB;
}

// ---------------------------------------------------------------------------
// Fallback: fp32 row-per-wave kernel (row_ptr version).
// ---------------------------------------------------------------------------
__global__ void __launch_bounds__(256) appnp_row_fp32(
    const int* __restrict__ row_ptr,
    const int* __restrict__ ecol,
    const float* __restrict__ evals,
    const float* __restrict__ h,
    const float* __restrict__ h0,
    float* __restrict__ out) {
    const int wave_id = (blockIdx.x * blockDim.x + threadIdx.x) >> 6;
    const int lane = threadIdx.x & 63;
    if (wave_id >= N_NODES) return;
    const int row = wave_id;
    const int seg_start = row_ptr[row];
    const int seg_end   = row_ptr[row + 1];
    float acc = 0.0f;
    for (int e = seg_start; e < seg_end; ++e)
        acc = fmaf(evals[e], h[(size_t)ecol[e] * D + lane], acc);
    const size_t oidx = (size_t)row * D + lane;
    out[oidx] = (1.0f - ALPHA) * acc + ALPHA * h0[oidx];
}

// Last-resort fallback: binary search, no workspace at all.
__global__ void __launch_bounds__(256) appnp_row_bsearch(
    const int* __restrict__ erow,
    const int* __restrict__ ecol,
    const float* __restrict__ evals,
    const float* __restrict__ h,
    const float* __restrict__ h0,
    float* __restrict__ out,
    int n_edges) {
    const int wave_id = (blockIdx.x * blockDim.x + threadIdx.x) >> 6;
    const int lane = threadIdx.x & 63;
    if (wave_id >= N_NODES) return;
    const int row = wave_id;
    int lo = 0, hi = n_edges;
    while (lo < hi) { int mid = (lo + hi) >> 1; if (erow[mid] < row) lo = mid + 1; else hi = mid; }
    const int seg_start = lo;
    hi = n_edges;
    while (lo < hi) { int mid = (lo + hi) >> 1; if (erow[mid] < row + 1) lo = mid + 1; else hi = mid; }
    const int seg_end = lo;
    float acc = 0.0f;
    for (int e = seg_start; e < seg_end; ++e)
        acc = fmaf(evals[e], h[(size_t)ecol[e] * D + lane], acc);
    const size_t oidx = (size_t)row * D + lane;
    out[oidx] = (1.0f - ALPHA) * acc + ALPHA * h0[oidx];
}

extern "C" void kernel_launch(void* const* d_in, const int* in_sizes, int n_in,
                              void* d_out, int out_size, void* d_ws, size_t ws_size,
                              hipStream_t stream) {
    const int*   erow  = (const int*)d_in[0];
    const int*   ecol  = (const int*)d_in[1];
    const float* evals = (const float*)d_in[2];
    const float* h     = (const float*)d_in[3];
    const float* h0    = (const float*)d_in[4];
    float* out = (float*)d_out;
    const int n_edges = in_sizes[0];

    const size_t rowptr_bytes = (size_t)(N_NODES + 1) * sizeof(int);
    const size_t rowptr_pad   = (rowptr_bytes + 255) & ~(size_t)255;
    const size_t hb_bytes     = (size_t)N_NODES * D * sizeof(unsigned short);

    if (ws_size >= rowptr_pad + hb_bytes) {
        int* row_ptr = (int*)d_ws;
        unsigned int* hb_packed = (unsigned int*)((char*)d_ws + rowptr_pad);
        build_row_ptr<<<(n_edges + 255) / 256, 256, 0, stream>>>(
            erow, row_ptr, n_edges);
        const int n4 = N_NODES * D / 4;
        convert_h_bf16<<<2048, 256, 0, stream>>>(h, hb_packed, n4);
        // 8 threads per row -> N*8 threads -> exactly 3125 blocks of 256
        const int grid = (N_NODES * 8 + 255) / 256;
        appnp_group_bf16<<<grid, 256, 0, stream>>>(
            row_ptr, ecol, evals, (const unsigned short*)hb_packed, h0, out);
    } else if (ws_size >= rowptr_bytes) {
        int* row_ptr = (int*)d_ws;
        build_row_ptr<<<(n_edges + 255) / 256, 256, 0, stream>>>(
            erow, row_ptr, n_edges);
        const int grid = (N_NODES + 3) / 4;
        appnp_row_fp32<<<grid, 256, 0, stream>>>(
            row_ptr, ecol, evals, h, h0, out);
    } else {
        const int grid = (N_NODES + 3) / 4;
        appnp_row_bsearch<<<grid, 256, 0, stream>>>(
            erow, ecol, evals, h, h0, out, n_edges);
    }
}

// Round 5
// 47.736 us; speedup vs baseline: 1.2925x; 1.2925x over previous
//
#include <hip/hip_runtime.h>

#define N_NODES 100000
#define D 64
#define ALPHA 0.2f

__device__ __forceinline__ float bf_lo(unsigned int u) {
    union { unsigned int u; float f; } c; c.u = u << 16; return c.f;
}
__device__ __forceinline__ float bf_hi(unsigned int u) {
    union { unsigned int u; float f; } c; c.u = u & 0xFFFF0000u; return c.f;
}

// ---------------------------------------------------------------------------
// Fused prologue (one launch): grid-stride over two independent ranges.
//  Task A: convert h (fp32) -> bf16 RNE, packed 2/uint  (n4 = N*64/4 iters)
//  Task B: build row_ptr[N+1] from sorted erow          (n_edges iters)
// ---------------------------------------------------------------------------
__global__ void __launch_bounds__(256) prologue_kernel(
    const int* __restrict__ erow, int* __restrict__ row_ptr,
    const float* __restrict__ h, unsigned int* __restrict__ hbp,
    int n_edges, int n4) {
    const int stride = gridDim.x * blockDim.x;
    const int gid = blockIdx.x * blockDim.x + threadIdx.x;
    for (int i = gid; i < n4; i += stride) {
        const float4 f = reinterpret_cast<const float4*>(h)[i];
        union { float f; unsigned int u; } c0, c1, c2, c3;
        c0.f = f.x; c1.f = f.y; c2.f = f.z; c3.f = f.w;
        const unsigned int b0 = (c0.u + 0x7FFFu + ((c0.u >> 16) & 1u)) >> 16;
        const unsigned int b1 = (c1.u + 0x7FFFu + ((c1.u >> 16) & 1u)) >> 16;
        const unsigned int b2 = (c2.u + 0x7FFFu + ((c2.u >> 16) & 1u)) >> 16;
        const unsigned int b3 = (c3.u + 0x7FFFu + ((c3.u >> 16) & 1u)) >> 16;
        uint2 o;
        o.x = b0 | (b1 << 16);
        o.y = b2 | (b3 << 16);
        reinterpret_cast<uint2*>(hbp)[i] = o;
    }
    for (int e = gid; e < n_edges; e += stride) {
        const int r = erow[e];
        const int rprev = (e == 0) ? -1 : erow[e - 1];
        for (int rr = rprev + 1; rr <= r; ++rr) row_ptr[rr] = e;
        if (e == n_edges - 1) {
            for (int rr = r + 1; rr <= N_NODES; ++rr) row_ptr[rr] = n_edges;
        }
    }
}

// ---------------------------------------------------------------------------
// Main kernel: 8 groups x 8 lanes per wave, one row per group, lane owns 8
// dims in registers (no cross-lane reduce). Inner loop is BRANCH-FREE:
// addresses clamped with min(i+k, last) so every load is unconditional;
// out-of-range edges contribute 0 via cndmask on the value. 8 independent
// gathers cluster before the first waitcnt -> MLP ~8 per wave.
// ---------------------------------------------------------------------------
__global__ void __launch_bounds__(256) appnp_group_bf16(
    const int* __restrict__ row_ptr,
    const int* __restrict__ ecol,
    const float* __restrict__ evals,
    const unsigned short* __restrict__ hb,   // bf16 h, row stride 64 elems
    const float* __restrict__ h0,
    float* __restrict__ out) {
    const int tid = blockIdx.x * blockDim.x + threadIdx.x;
    const int row = tid >> 3;          // one row per 8-lane group
    const int l = threadIdx.x & 7;     // dim octet: dims 8l..8l+7
    if (row >= N_NODES) return;

    const int s    = row_ptr[row];
    const int len  = row_ptr[row + 1] - s;
    const int last = len - 1;

    float a0 = 0.f, a1 = 0.f, a2 = 0.f, a3 = 0.f,
          a4 = 0.f, a5 = 0.f, a6 = 0.f, a7 = 0.f;

    const unsigned short* hl = hb + (l << 3);  // lane's 16-B column slice

    for (int i = 0; i < len; i += 8) {
        int   cc[8];
        float vv[8];
        #pragma unroll
        for (int k = 0; k < 8; ++k) {
            const int e = s + min(i + k, last);   // always a valid index
            cc[k] = ecol[e];                       // unconditional load
            const float v = evals[e];              // unconditional load
            vv[k] = (i + k < len) ? v : 0.f;       // select, not branch
        }
        uint4 pp[8];
        #pragma unroll
        for (int k = 0; k < 8; ++k) {
            pp[k] = *reinterpret_cast<const uint4*>(
                hl + ((size_t)cc[k] << 6));        // unconditional gather
        }
        #pragma unroll
        for (int k = 0; k < 8; ++k) {
            const float v = vv[k];
            const uint4 p = pp[k];
            a0 = fmaf(v, bf_lo(p.x), a0); a1 = fmaf(v, bf_hi(p.x), a1);
            a2 = fmaf(v, bf_lo(p.y), a2); a3 = fmaf(v, bf_hi(p.y), a3);
            a4 = fmaf(v, bf_lo(p.z), a4); a5 = fmaf(v, bf_hi(p.z), a5);
            a6 = fmaf(v, bf_lo(p.w), a6); a7 = fmaf(v, bf_hi(p.w), a7);
        }
    }

    // Epilogue: lane owns out[row][8l..8l+7]; wave-wide = contiguous 2 KB.
    const size_t o = ((size_t)row << 6) + (l << 3);
    const float4 h0a = *reinterpret_cast<const float4*>(&h0[o]);
    const float4 h0b = *reinterpret_cast<const float4*>(&h0[o + 4]);
    const float w = 1.0f - ALPHA;
    float4 oA, oB;
    oA.x = fmaf(w, a0, ALPHA * h0a.x);
    oA.y = fmaf(w, a1, ALPHA * h0a.y);
    oA.z = fmaf(w, a2, ALPHA * h0a.z);
    oA.w = fmaf(w, a3, ALPHA * h0a.w);
    oB.x = fmaf(w, a4, ALPHA * h0b.x);
    oB.y = fmaf(w, a5, ALPHA * h0b.y);
    oB.z = fmaf(w, a6, ALPHA * h0b.z);
    oB.w = fmaf(w, a7, ALPHA * h0b.w);
    *reinterpret_cast<float4*>(&out[o])     = oA;
    *reinterpret_cast<float4*>(&out[o + 4]) = oB;
}

// ---------------------------------------------------------------------------
// Fallbacks (workspace too small) — correctness-first paths.
// ---------------------------------------------------------------------------
__global__ void __launch_bounds__(256) build_row_ptr(
    const int* __restrict__ erow, int* __restrict__ row_ptr, int n_edges) {
    const int e = blockIdx.x * blockDim.x + threadIdx.x;
    if (e >= n_edges) return;
    const int r = erow[e];
    const int rprev = (e == 0) ? -1 : erow[e - 1];
    for (int rr = rprev + 1; rr <= r; ++rr) row_ptr[rr] = e;
    if (e == n_edges - 1) {
        for (int rr = r + 1; rr <= N_NODES; ++rr) row_ptr[rr] = n_edges;
    }
}

__global__ void __launch_bounds__(256) appnp_row_fp32(
    const int* __restrict__ row_ptr,
    const int* __restrict__ ecol,
    const float* __restrict__ evals,
    const float* __restrict__ h,
    const float* __restrict__ h0,
    float* __restrict__ out) {
    const int wave_id = (blockIdx.x * blockDim.x + threadIdx.x) >> 6;
    const int lane = threadIdx.x & 63;
    if (wave_id >= N_NODES) return;
    const int row = wave_id;
    const int seg_start = row_ptr[row];
    const int seg_end   = row_ptr[row + 1];
    float acc = 0.0f;
    for (int e = seg_start; e < seg_end; ++e)
        acc = fmaf(evals[e], h[(size_t)ecol[e] * D + lane], acc);
    const size_t oidx = (size_t)row * D + lane;
    out[oidx] = (1.0f - ALPHA) * acc + ALPHA * h0[oidx];
}

__global__ void __launch_bounds__(256) appnp_row_bsearch(
    const int* __restrict__ erow,
    const int* __restrict__ ecol,
    const float* __restrict__ evals,
    const float* __restrict__ h,
    const float* __restrict__ h0,
    float* __restrict__ out,
    int n_edges) {
    const int wave_id = (blockIdx.x * blockDim.x + threadIdx.x) >> 6;
    const int lane = threadIdx.x & 63;
    if (wave_id >= N_NODES) return;
    const int row = wave_id;
    int lo = 0, hi = n_edges;
    while (lo < hi) { int mid = (lo + hi) >> 1; if (erow[mid] < row) lo = mid + 1; else hi = mid; }
    const int seg_start = lo;
    hi = n_edges;
    while (lo < hi) { int mid = (lo + hi) >> 1; if (erow[mid] < row + 1) lo = mid + 1; else hi = mid; }
    const int seg_end = lo;
    float acc = 0.0f;
    for (int e = seg_start; e < seg_end; ++e)
        acc = fmaf(evals[e], h[(size_t)ecol[e] * D + lane], acc);
    const size_t oidx = (size_t)row * D + lane;
    out[oidx] = (1.0f - ALPHA) * acc + ALPHA * h0[oidx];
}

extern "C" void kernel_launch(void* const* d_in, const int* in_sizes, int n_in,
                              void* d_out, int out_size, void* d_ws, size_t ws_size,
                              hipStream_t stream) {
    const int*   erow  = (const int*)d_in[0];
    const int*   ecol  = (const int*)d_in[1];
    const float* evals = (const float*)d_in[2];
    const float* h     = (const float*)d_in[3];
    const float* h0    = (const float*)d_in[4];
    float* out = (float*)d_out;
    const int n_edges = in_sizes[0];

    const size_t rowptr_bytes = (size_t)(N_NODES + 1) * sizeof(int);
    const size_t rowptr_pad   = (rowptr_bytes + 255) & ~(size_t)255;
    const size_t hb_bytes     = (size_t)N_NODES * D * sizeof(unsigned short);

    if (ws_size >= rowptr_pad + hb_bytes) {
        int* row_ptr = (int*)d_ws;
        unsigned int* hb_packed = (unsigned int*)((char*)d_ws + rowptr_pad);
        const int n4 = N_NODES * D / 4;
        prologue_kernel<<<2048, 256, 0, stream>>>(
            erow, row_ptr, h, hb_packed, n_edges, n4);
        // 8 threads per row -> exactly 3125 blocks of 256
        const int grid = (N_NODES * 8 + 255) / 256;
        appnp_group_bf16<<<grid, 256, 0, stream>>>(
            row_ptr, ecol, evals, (const unsigned short*)hb_packed, h0, out);
    } else if (ws_size >= rowptr_bytes) {
        int* row_ptr = (int*)d_ws;
        build_row_ptr<<<(n_edges + 255) / 256, 256, 0, stream>>>(
            erow, row_ptr, n_edges);
        const int grid = (N_NODES + 3) / 4;
        appnp_row_fp32<<<grid, 256, 0, stream>>>(
            row_ptr, ecol, evals, h, h0, out);
    } else {
        const int grid = (N_NODES + 3) / 4;
        appnp_row_bsearch<<<grid, 256, 0, stream>>>(
            erow, ecol, evals, h, h0, out, n_edges);
    }
}

// Round 6
// 47.089 us; speedup vs baseline: 1.3103x; 1.0137x over previous
//
#include <hip/hip_runtime.h>

#define N_NODES 100000
#define D 64
#define ALPHA 0.2f

__device__ __forceinline__ float bf_lo(unsigned int u) {
    union { unsigned int u; float f; } c; c.u = u << 16; return c.f;
}
__device__ __forceinline__ float bf_hi(unsigned int u) {
    union { unsigned int u; float f; } c; c.u = u & 0xFFFF0000u; return c.f;
}

// ---------------------------------------------------------------------------
// Fused prologue (one launch, grid-stride over two independent ranges):
//  Task A: convert h (fp32) -> bf16 RNE, packed 2/uint  (n4 = N*64/4 iters)
//  Task B: build row_ptr[N+1] from sorted erow          (n_edges iters)
// HBM-bound (~51 MB): ~8 us, at roofline.
// ---------------------------------------------------------------------------
__global__ void __launch_bounds__(256) prologue_kernel(
    const int* __restrict__ erow, int* __restrict__ row_ptr,
    const float* __restrict__ h, unsigned int* __restrict__ hbp,
    int n_edges, int n4) {
    const int stride = gridDim.x * blockDim.x;
    const int gid = blockIdx.x * blockDim.x + threadIdx.x;
    for (int i = gid; i < n4; i += stride) {
        const float4 f = reinterpret_cast<const float4*>(h)[i];
        union { float f; unsigned int u; } c0, c1, c2, c3;
        c0.f = f.x; c1.f = f.y; c2.f = f.z; c3.f = f.w;
        const unsigned int b0 = (c0.u + 0x7FFFu + ((c0.u >> 16) & 1u)) >> 16;
        const unsigned int b1 = (c1.u + 0x7FFFu + ((c1.u >> 16) & 1u)) >> 16;
        const unsigned int b2 = (c2.u + 0x7FFFu + ((c2.u >> 16) & 1u)) >> 16;
        const unsigned int b3 = (c3.u + 0x7FFFu + ((c3.u >> 16) & 1u)) >> 16;
        uint2 o;
        o.x = b0 | (b1 << 16);
        o.y = b2 | (b3 << 16);
        reinterpret_cast<uint2*>(hbp)[i] = o;
    }
    for (int e = gid; e < n_edges; e += stride) {
        const int r = erow[e];
        const int rprev = (e == 0) ? -1 : erow[e - 1];
        for (int rr = rprev + 1; rr <= r; ++rr) row_ptr[rr] = e;
        if (e == n_edges - 1) {
            for (int rr = r + 1; rr <= N_NODES; ++rr) row_ptr[rr] = n_edges;
        }
    }
}

// ---------------------------------------------------------------------------
// Main kernel: 16 lanes per row = 2 sub-groups x 8 lanes; sub 0 takes the
// first ceil(len/2) edges, sub 1 the rest (contiguous halves). Lane owns 8
// dims in registers. Branch-free clamped 4-deep unroll per sub -> 8 gathers
// in flight per row. One shfl_xor(8) combines the two halves. 25k waves of
// half-length chains (vs 12.5k full) -> ~3 residency rounds, better fill.
// Block = 128 (8 rows) for fine-grained retirement. Grid 12500 exact.
// ---------------------------------------------------------------------------
__global__ void __launch_bounds__(128) appnp_half_bf16(
    const int* __restrict__ row_ptr,
    const int* __restrict__ ecol,
    const float* __restrict__ evals,
    const unsigned short* __restrict__ hb,   // bf16 h, row stride 64 elems
    const float* __restrict__ h0,
    float* __restrict__ out) {
    const int row = (blockIdx.x << 3) + (threadIdx.x >> 4);  // 8 rows/block
    const int sub = (threadIdx.x >> 3) & 1;                  // half selector
    const int l   = threadIdx.x & 7;                         // dim octet
    if (row >= N_NODES) return;

    const int s   = row_ptr[row];
    const int len = row_ptr[row + 1] - s;
    const int hlen = (len + 1) >> 1;                 // ceil(len/2)
    const int my_len = sub ? (len - hlen) : hlen;    // this sub's edge count
    const int my_s   = s + (sub ? hlen : 0);
    const int last   = my_len - 1;                   // may be -1 (empty)

    float a0 = 0.f, a1 = 0.f, a2 = 0.f, a3 = 0.f,
          a4 = 0.f, a5 = 0.f, a6 = 0.f, a7 = 0.f;

    const unsigned short* hl = hb + (l << 3);        // lane's 16-B column

    for (int i = 0; i < my_len; i += 4) {
        int   cc[4];
        float vv[4];
        #pragma unroll
        for (int k = 0; k < 4; ++k) {
            const int e = my_s + min(i + k, last);   // always valid when len>0
            cc[k] = ecol[e];                         // unconditional load
            const float v = evals[e];                // unconditional load
            vv[k] = (i + k < my_len) ? v : 0.f;      // value select, no branch
        }
        uint4 pp[4];
        #pragma unroll
        for (int k = 0; k < 4; ++k) {
            pp[k] = *reinterpret_cast<const uint4*>(
                hl + ((size_t)cc[k] << 6));          // unconditional gather
        }
        #pragma unroll
        for (int k = 0; k < 4; ++k) {
            const float v = vv[k];
            const uint4 p = pp[k];
            a0 = fmaf(v, bf_lo(p.x), a0); a1 = fmaf(v, bf_hi(p.x), a1);
            a2 = fmaf(v, bf_lo(p.y), a2); a3 = fmaf(v, bf_hi(p.y), a3);
            a4 = fmaf(v, bf_lo(p.z), a4); a5 = fmaf(v, bf_hi(p.z), a5);
            a6 = fmaf(v, bf_lo(p.w), a6); a7 = fmaf(v, bf_hi(p.w), a7);
        }
    }

    // Combine the two halves: lanes differing in bit 3 hold the same dims.
    a0 += __shfl_xor(a0, 8); a1 += __shfl_xor(a1, 8);
    a2 += __shfl_xor(a2, 8); a3 += __shfl_xor(a3, 8);
    a4 += __shfl_xor(a4, 8); a5 += __shfl_xor(a5, 8);
    a6 += __shfl_xor(a6, 8); a7 += __shfl_xor(a7, 8);

    if (sub == 0) {
        const size_t o = ((size_t)row << 6) + (l << 3);
        const float4 h0a = *reinterpret_cast<const float4*>(&h0[o]);
        const float4 h0b = *reinterpret_cast<const float4*>(&h0[o + 4]);
        const float w = 1.0f - ALPHA;
        float4 oA, oB;
        oA.x = fmaf(w, a0, ALPHA * h0a.x);
        oA.y = fmaf(w, a1, ALPHA * h0a.y);
        oA.z = fmaf(w, a2, ALPHA * h0a.z);
        oA.w = fmaf(w, a3, ALPHA * h0a.w);
        oB.x = fmaf(w, a4, ALPHA * h0b.x);
        oB.y = fmaf(w, a5, ALPHA * h0b.y);
        oB.z = fmaf(w, a6, ALPHA * h0b.z);
        oB.w = fmaf(w, a7, ALPHA * h0b.w);
        *reinterpret_cast<float4*>(&out[o])     = oA;
        *reinterpret_cast<float4*>(&out[o + 4]) = oB;
    }
}

// ---------------------------------------------------------------------------
// Fallbacks (workspace too small) — correctness-first paths.
// ---------------------------------------------------------------------------
__global__ void __launch_bounds__(256) build_row_ptr(
    const int* __restrict__ erow, int* __restrict__ row_ptr, int n_edges) {
    const int e = blockIdx.x * blockDim.x + threadIdx.x;
    if (e >= n_edges) return;
    const int r = erow[e];
    const int rprev = (e == 0) ? -1 : erow[e - 1];
    for (int rr = rprev + 1; rr <= r; ++rr) row_ptr[rr] = e;
    if (e == n_edges - 1) {
        for (int rr = r + 1; rr <= N_NODES; ++rr) row_ptr[rr] = n_edges;
    }
}

__global__ void __launch_bounds__(256) appnp_row_fp32(
    const int* __restrict__ row_ptr,
    const int* __restrict__ ecol,
    const float* __restrict__ evals,
    const float* __restrict__ h,
    const float* __restrict__ h0,
    float* __restrict__ out) {
    const int wave_id = (blockIdx.x * blockDim.x + threadIdx.x) >> 6;
    const int lane = threadIdx.x & 63;
    if (wave_id >= N_NODES) return;
    const int row = wave_id;
    const int seg_start = row_ptr[row];
    const int seg_end   = row_ptr[row + 1];
    float acc = 0.0f;
    for (int e = seg_start; e < seg_end; ++e)
        acc = fmaf(evals[e], h[(size_t)ecol[e] * D + lane], acc);
    const size_t oidx = (size_t)row * D + lane;
    out[oidx] = (1.0f - ALPHA) * acc + ALPHA * h0[oidx];
}

__global__ void __launch_bounds__(256) appnp_row_bsearch(
    const int* __restrict__ erow,
    const int* __restrict__ ecol,
    const float* __restrict__ evals,
    const float* __restrict__ h,
    const float* __restrict__ h0,
    float* __restrict__ out,
    int n_edges) {
    const int wave_id = (blockIdx.x * blockDim.x + threadIdx.x) >> 6;
    const int lane = threadIdx.x & 63;
    if (wave_id >= N_NODES) return;
    const int row = wave_id;
    int lo = 0, hi = n_edges;
    while (lo < hi) { int mid = (lo + hi) >> 1; if (erow[mid] < row) lo = mid + 1; else hi = mid; }
    const int seg_start = lo;
    hi = n_edges;
    while (lo < hi) { int mid = (lo + hi) >> 1; if (erow[mid] < row + 1) lo = mid + 1; else hi = mid; }
    const int seg_end = lo;
    float acc = 0.0f;
    for (int e = seg_start; e < seg_end; ++e)
        acc = fmaf(evals[e], h[(size_t)ecol[e] * D + lane], acc);
    const size_t oidx = (size_t)row * D + lane;
    out[oidx] = (1.0f - ALPHA) * acc + ALPHA * h0[oidx];
}

extern "C" void kernel_launch(void* const* d_in, const int* in_sizes, int n_in,
                              void* d_out, int out_size, void* d_ws, size_t ws_size,
                              hipStream_t stream) {
    const int*   erow  = (const int*)d_in[0];
    const int*   ecol  = (const int*)d_in[1];
    const float* evals = (const float*)d_in[2];
    const float* h     = (const float*)d_in[3];
    const float* h0    = (const float*)d_in[4];
    float* out = (float*)d_out;
    const int n_edges = in_sizes[0];

    const size_t rowptr_bytes = (size_t)(N_NODES + 1) * sizeof(int);
    const size_t rowptr_pad   = (rowptr_bytes + 255) & ~(size_t)255;
    const size_t hb_bytes     = (size_t)N_NODES * D * sizeof(unsigned short);

    if (ws_size >= rowptr_pad + hb_bytes) {
        int* row_ptr = (int*)d_ws;
        unsigned int* hb_packed = (unsigned int*)((char*)d_ws + rowptr_pad);
        const int n4 = N_NODES * D / 4;
        prologue_kernel<<<2048, 256, 0, stream>>>(
            erow, row_ptr, h, hb_packed, n_edges, n4);
        // 16 threads per row, 8 rows per 128-thread block -> 12500 blocks
        const int grid = (N_NODES + 7) / 8;
        appnp_half_bf16<<<grid, 128, 0, stream>>>(
            row_ptr, ecol, evals, (const unsigned short*)hb_packed, h0, out);
    } else if (ws_size >= rowptr_bytes) {
        int* row_ptr = (int*)d_ws;
        build_row_ptr<<<(n_edges + 255) / 256, 256, 0, stream>>>(
            erow, row_ptr, n_edges);
        const int grid = (N_NODES + 3) / 4;
        appnp_row_fp32<<<grid, 256, 0, stream>>>(
            row_ptr, ecol, evals, h, h0, out);
    } else {
        const int grid = (N_NODES + 3) / 4;
        appnp_row_bsearch<<<grid, 256, 0, stream>>>(
            erow, ecol, evals, h, h0, out, n_edges);
    }
}